// Round 8
// baseline (524.473 us; speedup 1.0000x reference)
//
#include <hip/hip_runtime.h>
#include <math.h>

#define T_SEQ     2048
#define HIDDEN_   2048
#define NUM_HEADS 16
#define NUM_KV    8
#define HEAD_DIM  128
#define Q_SIZE    2048
#define KV_SIZE   1024
#define QKV_N     4096
#define QK_N      3072
#define EPS_      1e-6f

typedef __attribute__((ext_vector_type(8))) short short8;
typedef __attribute__((ext_vector_type(4))) float floatx4;

__device__ __forceinline__ unsigned short f2bf(float f) {
    unsigned int u = __float_as_uint(f);
    u += 0x7fffu + ((u >> 16) & 1u);     // RNE
    return (unsigned short)(u >> 16);
}
__device__ __forceinline__ float b2f(unsigned short u) {
    return __uint_as_float((unsigned int)u << 16);
}

__device__ __forceinline__ void stage16(const unsigned short* g, unsigned short* lds_base) {
    __builtin_amdgcn_global_load_lds(
        (const __attribute__((address_space(1))) unsigned int*)g,
        (__attribute__((address_space(3))) unsigned int*)lds_base, 16, 0, 0);
}

// ---------------------------------------------------------------------------
// Fused fp32 -> bf16 conversion of hidden, qkv_w, o_w in ONE launch.
// ---------------------------------------------------------------------------
#define H4 (T_SEQ * HIDDEN_ / 4)
#define W4 (QKV_N * HIDDEN_ / 4)
#define O4 (Q_SIZE * HIDDEN_ / 4)

__global__ __launch_bounds__(256) void convert_all(
    const float* __restrict__ hidden, const float* __restrict__ qkv_w,
    const float* __restrict__ o_w, unsigned short* __restrict__ hbf,
    unsigned short* __restrict__ wbf, unsigned short* __restrict__ obf)
{
    int i = blockIdx.x * 256 + threadIdx.x;
    const float4* src;
    ushort4* dst;
    int j;
    if (i < H4)            { src = (const float4*)hidden; dst = (ushort4*)hbf; j = i; }
    else if (i < H4 + W4)  { src = (const float4*)qkv_w;  dst = (ushort4*)wbf; j = i - H4; }
    else                   { src = (const float4*)o_w;    dst = (ushort4*)obf; j = i - H4 - W4;
                             if (j >= O4) return; }
    float4 v = src[j];
    ushort4 o;
    o.x = f2bf(v.x); o.y = f2bf(v.y); o.z = f2bf(v.z); o.w = f2bf(v.w);
    dst[j] = o;
}

// ---------------------------------------------------------------------------
// bf16 MFMA GEMM (NT), 128x128 tile, 4 waves.
// MODE 0: C fp32 row-major (O-projection).
// MODE 1 (QKV): col-tiles are head-aligned. q/k tiles (bn < 3072): fused
// RMSNorm + RoPE in the epilogue -> Qb (scale folded) / Kb. v tiles
// (bn >= 3072): store transposed into Vt[kv][128][T].
// ---------------------------------------------------------------------------
template<int MODE>
__global__ __launch_bounds__(256) void gemm_nt_bf16(
    const unsigned short* __restrict__ A, const unsigned short* __restrict__ B,
    float* __restrict__ C,
    unsigned short* __restrict__ Qb, unsigned short* __restrict__ Kb,
    unsigned short* __restrict__ Vt,
    const int* __restrict__ positions,
    const float* __restrict__ qw, const float* __restrict__ kw,
    int M, int N, int K)
{
    __shared__ unsigned short As[128 * 32];
    __shared__ unsigned short Bs[128 * 32];
    const int tid  = threadIdx.x;
    const int w    = tid >> 6;
    const int lane = tid & 63;
    const int colL = lane & 15;
    const int quad = lane >> 4;
    const int bm = blockIdx.y * 128;
    const int bn = blockIdx.x * 128;
    const int wm = (w & 1) * 64;
    const int wn = (w >> 1) * 64;

    floatx4 acc[4][4];
    #pragma unroll
    for (int i = 0; i < 4; ++i)
        #pragma unroll
        for (int j = 0; j < 4; ++j)
            acc[i][j] = (floatx4){0.f, 0.f, 0.f, 0.f};

    int s_r[2], s_lc[2];
    #pragma unroll
    for (int cc = 0; cc < 2; ++cc) {
        int s = cc * 256 + tid;
        int r = s >> 2, pc = s & 3;
        s_r[cc] = r;
        s_lc[cc] = pc ^ ((r >> 1) & 3);
    }

    for (int k0 = 0; k0 < K; k0 += 32) {
        __syncthreads();
        #pragma unroll
        for (int cc = 0; cc < 2; ++cc) {
            unsigned short* ldsA = &As[(cc * 256 + w * 64) * 8];
            unsigned short* ldsB = &Bs[(cc * 256 + w * 64) * 8];
            stage16(A + (size_t)(bm + s_r[cc]) * K + k0 + s_lc[cc] * 8, ldsA);
            stage16(B + (size_t)(bn + s_r[cc]) * K + k0 + s_lc[cc] * 8, ldsB);
        }
        __syncthreads();

        short8 af[4], bf[4];
        #pragma unroll
        for (int i = 0; i < 4; ++i) {
            int r = wm + i * 16 + colL;
            int pc = quad ^ ((r >> 1) & 3);
            af[i] = *(const short8*)&As[r * 32 + pc * 8];
        }
        #pragma unroll
        for (int j = 0; j < 4; ++j) {
            int r = wn + j * 16 + colL;
            int pc = quad ^ ((r >> 1) & 3);
            bf[j] = *(const short8*)&Bs[r * 32 + pc * 8];
        }
        #pragma unroll
        for (int i = 0; i < 4; ++i)
            #pragma unroll
            for (int j = 0; j < 4; ++j)
                acc[i][j] = __builtin_amdgcn_mfma_f32_16x16x32_bf16(af[i], bf[j], acc[i][j], 0, 0, 0);
    }

    if constexpr (MODE == 0) {
        #pragma unroll
        for (int i = 0; i < 4; ++i)
            #pragma unroll
            for (int j = 0; j < 4; ++j)
                #pragma unroll
                for (int rr = 0; rr < 4; ++rr) {
                    int row = bm + wm + i * 16 + quad * 4 + rr;
                    int cc2 = bn + wn + j * 16 + colL;
                    C[(size_t)row * N + cc2] = acc[i][j][rr];
                }
    } else {
        if (bn < QK_N) {
            // ------------------- fused RMSNorm + RoPE epilogue -------------------
            __shared__ float sums[2][128];
            __shared__ unsigned short xnL[128 * 132];   // [d][row], stride 132

            float p[4][4];
            #pragma unroll
            for (int i = 0; i < 4; ++i)
                #pragma unroll
                for (int rr = 0; rr < 4; ++rr) {
                    float s = 0.f;
                    #pragma unroll
                    for (int j = 0; j < 4; ++j)
                        s = fmaf(acc[i][j][rr], acc[i][j][rr], s);
                    p[i][rr] = s;
                }
            #pragma unroll
            for (int off = 1; off < 16; off <<= 1)
                #pragma unroll
                for (int i = 0; i < 4; ++i)
                    #pragma unroll
                    for (int rr = 0; rr < 4; ++rr)
                        p[i][rr] += __shfl_xor(p[i][rr], off, 64);
            if (colL == 0) {
                #pragma unroll
                for (int i = 0; i < 4; ++i)
                    #pragma unroll
                    for (int rr = 0; rr < 4; ++rr)
                        sums[wn >> 6][wm + i * 16 + quad * 4 + rr] = p[i][rr];
            }
            __syncthreads();

            float inv_r[4][4];
            #pragma unroll
            for (int i = 0; i < 4; ++i)
                #pragma unroll
                for (int rr = 0; rr < 4; ++rr) {
                    int row = wm + i * 16 + quad * 4 + rr;
                    float tot = sums[0][row] + sums[1][row];
                    inv_r[i][rr] = rsqrtf(tot * (1.0f / HEAD_DIM) + EPS_);
                }

            const float* nw = (bn < Q_SIZE) ? qw : kw;
            float wv[4];
            #pragma unroll
            for (int j = 0; j < 4; ++j)
                wv[j] = nw[wn + j * 16 + colL];

            #pragma unroll
            for (int i = 0; i < 4; ++i)
                #pragma unroll
                for (int j = 0; j < 4; ++j) {
                    ushort4 pk;
                    pk.x = f2bf(acc[i][j][0] * inv_r[i][0] * wv[j]);
                    pk.y = f2bf(acc[i][j][1] * inv_r[i][1] * wv[j]);
                    pk.z = f2bf(acc[i][j][2] * inv_r[i][2] * wv[j]);
                    pk.w = f2bf(acc[i][j][3] * inv_r[i][3] * wv[j]);
                    int d = wn + j * 16 + colL;
                    *(ushort4*)&xnL[d * 132 + wm + i * 16 + quad * 4] = pk;
                }
            __syncthreads();

            const float l2r = 13.287712379549449f / 64.0f;
            float invf[4];
            #pragma unroll
            for (int j = 0; j < 4; ++j) {
                int fd = (wn + j * 16 + colL) & 63;
                invf[j] = exp2f(-(float)fd * l2r);
            }
            const bool hi = (wn != 0);
            const bool is_q = (bn < Q_SIZE);
            const int hq = bn >> 7;
            const int kvh = (bn - Q_SIZE) >> 7;

            #pragma unroll
            for (int i = 0; i < 4; ++i)
                #pragma unroll
                for (int rr = 0; rr < 4; ++rr) {
                    int row = wm + i * 16 + quad * 4 + rr;
                    float pos = (float)positions[bm + row];
                    #pragma unroll
                    for (int j = 0; j < 4; ++j) {
                        int d = wn + j * 16 + colL;
                        float own = acc[i][j][rr] * inv_r[i][rr] * wv[j];
                        float partner = b2f(xnL[(d ^ 64) * 132 + row]);
                        float s, c;
                        sincosf(pos * invf[j], &s, &c);
                        float outv = hi ? fmaf(own, c, partner * s)
                                        : fmaf(own, c, -partner * s);
                        if (is_q)
                            Qb[(size_t)(bm + row) * Q_SIZE + hq * HEAD_DIM + d]
                                = f2bf(outv * 0.08838834764831845f);
                        else
                            Kb[((size_t)kvh * T_SEQ + bm + row) * HEAD_DIM + d]
                                = f2bf(outv);
                    }
                }
        } else {
            const int kvh = (bn - QK_N) >> 7;
            #pragma unroll
            for (int i = 0; i < 4; ++i)
                #pragma unroll
                for (int j = 0; j < 4; ++j) {
                    int d = wn + j * 16 + colL;
                    int tok = bm + wm + i * 16 + quad * 4;
                    ushort4 o;
                    o.x = f2bf(acc[i][j][0]); o.y = f2bf(acc[i][j][1]);
                    o.z = f2bf(acc[i][j][2]); o.w = f2bf(acc[i][j][3]);
                    *(ushort4*)&Vt[((size_t)kvh * HEAD_DIM + d) * T_SEQ + tok] = o;
                }
        }
    }
}

// ---------------------------------------------------------------------------
// Flash attention: BK=64, split-K over 1024-token chunks, fixed-max softmax,
// ones-column l, heavy-first ordering — unchanged.
// ---------------------------------------------------------------------------
#define BQ 64
#define BK 64

__global__ __launch_bounds__(256) void attn_mfma(
    const unsigned short* __restrict__ Qb, const unsigned short* __restrict__ Kb,
    const unsigned short* __restrict__ Vt, unsigned short* __restrict__ ctxb,
    float* __restrict__ partO, float* __restrict__ partL)
{
    const int h = blockIdx.y;
    int qt, ch;
    {
        int x = blockIdx.x;
        if (x < 16) { qt = 16 + x; ch = 0; }
        else {
            int p = (x - 16) >> 1;
            if (((x - 16) & 1) == 0) { qt = 15 - p; ch = 0; }
            else                     { qt = 31 - p; ch = 1; }
        }
    }
    const int nch = (qt >= 16) ? 2 : 1;
    const int units = (ch == 0) ? ((qt + 1 < 16) ? qt + 1 : 16) : (qt + 1 - 16);
    const int q0 = qt * BQ;
    const int kv = h >> 1;
    const int tid = threadIdx.x;
    const int w = tid >> 6;
    const int lane = tid & 63;
    const int col = lane & 15;
    const int quad = lane >> 4;

    __shared__ unsigned short Ks[2][64 * 128];
    __shared__ unsigned short Vs[2][144 * 64];
    __shared__ unsigned short Ps[4][16][72];

    {
        int x = tid * 4;
        unsigned short vv = (x < 64) ? (unsigned short)0x3F80 : (unsigned short)0;
        ushort4 o = {vv, vv, vv, vv};
        *(ushort4*)&Vs[0][128 * 64 + x] = o;
        *(ushort4*)&Vs[1][128 * 64 + x] = o;
    }

    short8 qf[4];
    {
        const unsigned short* qp = Qb + (size_t)(q0 + w * 16 + col) * Q_SIZE + h * HEAD_DIM;
        #pragma unroll
        for (int c = 0; c < 4; ++c)
            qf[c] = *(const short8*)(qp + c * 32 + quad * 8);
    }

    const unsigned short* kg[4];
    const unsigned short* vg[4];
    #pragma unroll
    for (int it = 0; it < 4; ++it) {
        int s = it * 256 + tid;
        int kr = s >> 4, kp = s & 15, kj = kp ^ (kr & 15);
        kg[it] = Kb + (size_t)kv * T_SEQ * HEAD_DIM + kr * HEAD_DIM + kj * 8;
        int vr = s >> 3, vp = s & 7, vj = vp ^ (vr & 7);
        vg[it] = Vt + (size_t)kv * HEAD_DIM * T_SEQ + (size_t)vr * T_SEQ + vj * 8;
    }

    floatx4 Ob[9];
    #pragma unroll
    for (int cb = 0; cb < 9; ++cb) Ob[cb] = (floatx4){0.f, 0.f, 0.f, 0.f};

    const int wave_qmin = q0 + w * 16;
    const int wave_qmax = wave_qmin + 15;
    const int tok_base = ch * 1024;

    #pragma unroll
    for (int it = 0; it < 4; ++it) {
        stage16(kg[it] + (size_t)tok_base * HEAD_DIM, &Ks[0][(it * 256 + w * 64) * 8]);
        stage16(vg[it] + tok_base, &Vs[0][(it * 256 + w * 64) * 8]);
    }

    for (int u = 0; u < units; ++u) {
        const int t0 = tok_base + u * BK;
        __syncthreads();
        if (u + 1 < units) {
            const int tn = t0 + BK;
            const int b = (u + 1) & 1;
            #pragma unroll
            for (int it = 0; it < 4; ++it) {
                stage16(kg[it] + (size_t)tn * HEAD_DIM, &Ks[b][(it * 256 + w * 64) * 8]);
                stage16(vg[it] + tn, &Vs[b][(it * 256 + w * 64) * 8]);
            }
        }
        if (t0 > wave_qmax) continue;
        const unsigned short* ks = Ks[u & 1];
        const unsigned short* vs = Vs[u & 1];

        floatx4 S[4];
        #pragma unroll
        for (int cb = 0; cb < 4; ++cb) {
            floatx4 a = (floatx4){0.f, 0.f, 0.f, 0.f};
            #pragma unroll
            for (int c = 0; c < 4; ++c) {
                short8 kf = *(const short8*)&ks[((cb * 16 + col) * 16 + ((c * 4 + quad) ^ col)) * 8];
                a = __builtin_amdgcn_mfma_f32_16x16x32_bf16(kf, qf[c], a, 0, 0, 0);
            }
            S[cb] = a;
        }

        const int qr = q0 + w * 16 + col;
        if (t0 + 63 <= wave_qmin) {
            #pragma unroll
            for (int cb = 0; cb < 4; ++cb) {
                ushort4 pk;
                pk.x = f2bf(__expf(S[cb][0])); pk.y = f2bf(__expf(S[cb][1]));
                pk.z = f2bf(__expf(S[cb][2])); pk.w = f2bf(__expf(S[cb][3]));
                *(ushort4*)&Ps[w][col][cb * 16 + quad * 4] = pk;
            }
        } else {
            #pragma unroll
            for (int cb = 0; cb < 4; ++cb) {
                int kt = t0 + cb * 16 + quad * 4;
                ushort4 pk;
                pk.x = (kt + 0 <= qr) ? f2bf(__expf(S[cb][0])) : (unsigned short)0;
                pk.y = (kt + 1 <= qr) ? f2bf(__expf(S[cb][1])) : (unsigned short)0;
                pk.z = (kt + 2 <= qr) ? f2bf(__expf(S[cb][2])) : (unsigned short)0;
                pk.w = (kt + 3 <= qr) ? f2bf(__expf(S[cb][3])) : (unsigned short)0;
                *(ushort4*)&Ps[w][col][cb * 16 + quad * 4] = pk;
            }
        }

        short8 pf[2];
        pf[0] = *(const short8*)&Ps[w][col][quad * 8];
        pf[1] = *(const short8*)&Ps[w][col][32 + quad * 8];
        #pragma unroll
        for (int cb = 0; cb < 9; ++cb) {
            int vrow = cb * 16 + col;
            #pragma unroll
            for (int kk = 0; kk < 2; ++kk) {
                short8 vf = *(const short8*)&vs[(vrow * 8 + ((kk * 4 + quad) ^ (vrow & 7))) * 8];
                Ob[cb] = __builtin_amdgcn_mfma_f32_16x16x32_bf16(pf[kk], vf, Ob[cb], 0, 0, 0);
            }
        }
    }

    if (nch == 1) {
        #pragma unroll
        for (int r = 0; r < 4; ++r) {
            float l = __shfl(Ob[8][r], lane & 48);
            float rl = 1.0f / l;
            const int qrow = q0 + w * 16 + quad * 4 + r;
            #pragma unroll
            for (int cb = 0; cb < 8; ++cb)
                ctxb[(size_t)qrow * Q_SIZE + h * HEAD_DIM + cb * 16 + col] = f2bf(Ob[cb][r] * rl);
        }
    } else {
        const int slot = (h * 16 + (qt - 16)) * 2 + ch;
        float* po = partO + (size_t)slot * (BQ * HEAD_DIM);
        #pragma unroll
        for (int cb = 0; cb < 8; ++cb)
            #pragma unroll
            for (int r = 0; r < 4; ++r)
                po[(w * 16 + quad * 4 + r) * HEAD_DIM + cb * 16 + col] = Ob[cb][r];
        if (col == 0) {
            #pragma unroll
            for (int r = 0; r < 4; ++r)
                partL[slot * BQ + w * 16 + quad * 4 + r] = Ob[8][r];
        }
    }
}

// ---------------------------------------------------------------------------
// Combine: ctx[qt>=16] = (O0 + O1) / (l0 + l1) — unchanged.
// ---------------------------------------------------------------------------
__global__ __launch_bounds__(256) void combine(
    const float* __restrict__ partO, const float* __restrict__ partL,
    unsigned short* __restrict__ ctxb)
{
    const int h = blockIdx.x >> 4;
    const int qi = blockIdx.x & 15;
    const int q0 = (16 + qi) * 64;
    const int slot0 = (h * 16 + qi) * 2;
    const int tid = threadIdx.x;
    const int row = tid >> 2;
    const int seg = tid & 3;

    const float l = partL[slot0 * 64 + row] + partL[(slot0 + 1) * 64 + row];
    const float rl = 1.0f / l;
    const float* p0 = partO + (size_t)slot0 * 8192 + row * 128 + seg * 32;
    const float* p1 = p0 + 8192;
    unsigned short* dst = ctxb + (size_t)(q0 + row) * Q_SIZE + h * HEAD_DIM + seg * 32;
    #pragma unroll
    for (int m = 0; m < 8; ++m) {
        float4 a = *(const float4*)(p0 + m * 4);
        float4 b = *(const float4*)(p1 + m * 4);
        ushort4 o;
        o.x = f2bf((a.x + b.x) * rl); o.y = f2bf((a.y + b.y) * rl);
        o.z = f2bf((a.z + b.z) * rl); o.w = f2bf((a.w + b.w) * rl);
        *(ushort4*)(dst + m * 4) = o;
    }
}

// ---------------------------------------------------------------------------
extern "C" void kernel_launch(void* const* d_in, const int* in_sizes, int n_in,
                              void* d_out, int out_size, void* d_ws, size_t ws_size,
                              hipStream_t stream)
{
    const int*   positions = (const int*)d_in[0];
    const float* hidden    = (const float*)d_in[1];
    const float* qkv_w     = (const float*)d_in[2];
    const float* q_norm_w  = (const float*)d_in[3];
    const float* k_norm_w  = (const float*)d_in[4];
    const float* o_w       = (const float*)d_in[5];
    float* out = (float*)d_out;

    const size_t MB = 1024 * 1024;
    char* ws = (char*)d_ws;
    unsigned short* obf  = (unsigned short*)ws;                 // [0,8)   whole run
    unsigned short* hbf  = (unsigned short*)(ws + 8 * MB);      // [8,16)  dead after QKV GEMM
    unsigned short* wbf  = (unsigned short*)(ws + 16 * MB);     // [16,32) dead after QKV GEMM
    unsigned short* Vt   = (unsigned short*)(ws + 32 * MB);     // [32,36)
    unsigned short* Qb   = (unsigned short*)(ws + 36 * MB);     // [36,44)
    unsigned short* Kb   = (unsigned short*)(ws + 44 * MB);     // [44,48)
    unsigned short* ctxb = (unsigned short*)(ws + 48 * MB);     // [48,56)
    float* partL         = (float*)(ws + 8 * MB);               // [8,8.125) over dead hbf
    float* partO         = (float*)(ws + 16 * MB);              // [16,32) over dead wbf (16 MB!)

    convert_all<<<(H4 + W4 + O4 + 255) / 256, 256, 0, stream>>>(
        hidden, qkv_w, o_w, hbf, wbf, obf);
    gemm_nt_bf16<1><<<dim3(QKV_N / 128, T_SEQ / 128), 256, 0, stream>>>(
        hbf, wbf, nullptr, Qb, Kb, Vt, positions, q_norm_w, k_norm_w,
        T_SEQ, QKV_N, HIDDEN_);
    attn_mfma<<<dim3(48, NUM_HEADS), 256, 0, stream>>>(Qb, Kb, Vt, ctxb, partO, partL);
    combine<<<256, 256, 0, stream>>>(partO, partL, ctxb);
    gemm_nt_bf16<0><<<dim3(Q_SIZE / 128, T_SEQ / 128), 256, 0, stream>>>(
        ctxb, obf, out, nullptr, nullptr, nullptr, nullptr, nullptr, nullptr,
        T_SEQ, Q_SIZE, HIDDEN_);
}

// Round 9
// 283.056 us; speedup vs baseline: 1.8529x; 1.8529x over previous
//
#include <hip/hip_runtime.h>
#include <math.h>

#define T_SEQ     2048
#define HIDDEN_   2048
#define NUM_HEADS 16
#define NUM_KV    8
#define HEAD_DIM  128
#define Q_SIZE    2048
#define KV_SIZE   1024
#define QKV_N     4096
#define QK_N      3072
#define EPS_      1e-6f

typedef __attribute__((ext_vector_type(8))) short short8;
typedef __attribute__((ext_vector_type(4))) float floatx4;

__device__ __forceinline__ unsigned short f2bf(float f) {
    unsigned int u = __float_as_uint(f);
    u += 0x7fffu + ((u >> 16) & 1u);     // RNE
    return (unsigned short)(u >> 16);
}
__device__ __forceinline__ float b2f(unsigned short u) {
    return __uint_as_float((unsigned int)u << 16);
}

__device__ __forceinline__ void stage16(const unsigned short* g, unsigned short* lds_base) {
    __builtin_amdgcn_global_load_lds(
        (const __attribute__((address_space(1))) unsigned int*)g,
        (__attribute__((address_space(3))) unsigned int*)lds_base, 16, 0, 0);
}

// ---------------------------------------------------------------------------
// Fused fp32 -> bf16 conversion of hidden, qkv_w, o_w in ONE launch.
// ---------------------------------------------------------------------------
#define H4 (T_SEQ * HIDDEN_ / 4)
#define W4 (QKV_N * HIDDEN_ / 4)
#define O4 (Q_SIZE * HIDDEN_ / 4)

__global__ __launch_bounds__(256) void convert_all(
    const float* __restrict__ hidden, const float* __restrict__ qkv_w,
    const float* __restrict__ o_w, unsigned short* __restrict__ hbf,
    unsigned short* __restrict__ wbf, unsigned short* __restrict__ obf)
{
    int i = blockIdx.x * 256 + threadIdx.x;
    const float4* src;
    ushort4* dst;
    int j;
    if (i < H4)            { src = (const float4*)hidden; dst = (ushort4*)hbf; j = i; }
    else if (i < H4 + W4)  { src = (const float4*)qkv_w;  dst = (ushort4*)wbf; j = i - H4; }
    else                   { src = (const float4*)o_w;    dst = (ushort4*)obf; j = i - H4 - W4;
                             if (j >= O4) return; }
    float4 v = src[j];
    ushort4 o;
    o.x = f2bf(v.x); o.y = f2bf(v.y); o.z = f2bf(v.z); o.w = f2bf(v.w);
    dst[j] = o;
}

// ---------------------------------------------------------------------------
// bf16 MFMA GEMM (NT), 128x128 tile, 4 waves.
// MODE 0: C fp32 row-major (O-projection).
// MODE 1 (QKV): q/k tiles: fused RMSNorm + RoPE epilogue, two-phase so the
// accumulators die before the sincos loop (R8's spill bug). v tiles: store
// transposed into Vt[kv][128][T].
// ---------------------------------------------------------------------------
template<int MODE>
__global__ __launch_bounds__(256) void gemm_nt_bf16(
    const unsigned short* __restrict__ A, const unsigned short* __restrict__ B,
    float* __restrict__ C,
    unsigned short* __restrict__ Qb, unsigned short* __restrict__ Kb,
    unsigned short* __restrict__ Vt,
    const int* __restrict__ positions,
    const float* __restrict__ qw, const float* __restrict__ kw,
    int M, int N, int K)
{
    __shared__ unsigned short As[128 * 32];
    __shared__ unsigned short Bs[128 * 32];
    const int tid  = threadIdx.x;
    const int w    = tid >> 6;
    const int lane = tid & 63;
    const int colL = lane & 15;
    const int quad = lane >> 4;
    const int bm = blockIdx.y * 128;
    const int bn = blockIdx.x * 128;
    const int wm = (w & 1) * 64;
    const int wn = (w >> 1) * 64;

    floatx4 acc[4][4];
    #pragma unroll
    for (int i = 0; i < 4; ++i)
        #pragma unroll
        for (int j = 0; j < 4; ++j)
            acc[i][j] = (floatx4){0.f, 0.f, 0.f, 0.f};

    int s_r[2], s_lc[2];
    #pragma unroll
    for (int cc = 0; cc < 2; ++cc) {
        int s = cc * 256 + tid;
        int r = s >> 2, pc = s & 3;
        s_r[cc] = r;
        s_lc[cc] = pc ^ ((r >> 1) & 3);
    }

    for (int k0 = 0; k0 < K; k0 += 32) {
        __syncthreads();
        #pragma unroll
        for (int cc = 0; cc < 2; ++cc) {
            unsigned short* ldsA = &As[(cc * 256 + w * 64) * 8];
            unsigned short* ldsB = &Bs[(cc * 256 + w * 64) * 8];
            stage16(A + (size_t)(bm + s_r[cc]) * K + k0 + s_lc[cc] * 8, ldsA);
            stage16(B + (size_t)(bn + s_r[cc]) * K + k0 + s_lc[cc] * 8, ldsB);
        }
        __syncthreads();

        short8 af[4], bf[4];
        #pragma unroll
        for (int i = 0; i < 4; ++i) {
            int r = wm + i * 16 + colL;
            int pc = quad ^ ((r >> 1) & 3);
            af[i] = *(const short8*)&As[r * 32 + pc * 8];
        }
        #pragma unroll
        for (int j = 0; j < 4; ++j) {
            int r = wn + j * 16 + colL;
            int pc = quad ^ ((r >> 1) & 3);
            bf[j] = *(const short8*)&Bs[r * 32 + pc * 8];
        }
        #pragma unroll
        for (int i = 0; i < 4; ++i)
            #pragma unroll
            for (int j = 0; j < 4; ++j)
                acc[i][j] = __builtin_amdgcn_mfma_f32_16x16x32_bf16(af[i], bf[j], acc[i][j], 0, 0, 0);
    }

    if constexpr (MODE == 0) {
        #pragma unroll
        for (int i = 0; i < 4; ++i)
            #pragma unroll
            for (int j = 0; j < 4; ++j)
                #pragma unroll
                for (int rr = 0; rr < 4; ++rr) {
                    int row = bm + wm + i * 16 + quad * 4 + rr;
                    int cc2 = bn + wn + j * 16 + colL;
                    C[(size_t)row * N + cc2] = acc[i][j][rr];
                }
    } else {
        if (bn < QK_N) {
            // ---------- Phase A: RMSNorm, acc -> bf16 xnL, acc dies ----------
            __shared__ float sums[2][128];
            __shared__ unsigned short xnL[128 * 132];   // [d][row], stride 132

            float p[4][4];
            #pragma unroll
            for (int i = 0; i < 4; ++i)
                #pragma unroll
                for (int rr = 0; rr < 4; ++rr) {
                    float s = 0.f;
                    #pragma unroll
                    for (int j = 0; j < 4; ++j)
                        s = fmaf(acc[i][j][rr], acc[i][j][rr], s);
                    p[i][rr] = s;
                }
            #pragma unroll
            for (int off = 1; off < 16; off <<= 1)
                #pragma unroll
                for (int i = 0; i < 4; ++i)
                    #pragma unroll
                    for (int rr = 0; rr < 4; ++rr)
                        p[i][rr] += __shfl_xor(p[i][rr], off, 64);
            if (colL == 0) {
                #pragma unroll
                for (int i = 0; i < 4; ++i)
                    #pragma unroll
                    for (int rr = 0; rr < 4; ++rr)
                        sums[wn >> 6][wm + i * 16 + quad * 4 + rr] = p[i][rr];
            }
            __syncthreads();

            float inv_r[4][4];
            #pragma unroll
            for (int i = 0; i < 4; ++i)
                #pragma unroll
                for (int rr = 0; rr < 4; ++rr) {
                    int row = wm + i * 16 + quad * 4 + rr;
                    float tot = sums[0][row] + sums[1][row];
                    inv_r[i][rr] = rsqrtf(tot * (1.0f / HEAD_DIM) + EPS_);
                }

            const float* nw = (bn < Q_SIZE) ? qw : kw;
            float wv[4];
            #pragma unroll
            for (int j = 0; j < 4; ++j)
                wv[j] = nw[wn + j * 16 + colL];

            #pragma unroll
            for (int i = 0; i < 4; ++i)
                #pragma unroll
                for (int j = 0; j < 4; ++j) {
                    ushort4 pk;
                    pk.x = f2bf(acc[i][j][0] * inv_r[i][0] * wv[j]);
                    pk.y = f2bf(acc[i][j][1] * inv_r[i][1] * wv[j]);
                    pk.z = f2bf(acc[i][j][2] * inv_r[i][2] * wv[j]);
                    pk.w = f2bf(acc[i][j][3] * inv_r[i][3] * wv[j]);
                    int d = wn + j * 16 + colL;
                    *(ushort4*)&xnL[d * 132 + wm + i * 16 + quad * 4] = pk;
                }
            __syncthreads();
            // ---------- Phase B: RoPE from LDS only (no acc liveness) ----------
            // thread -> (row r = tid>>1, freq half p = tid&1); 32 sincos/thread,
            // each produces BOTH d and d+64 outputs; ushort4 vector stores.
            {
                const int r = tid >> 1;
                const int ph = tid & 1;
                const float pos = (float)positions[bm + r];
                const bool is_q = (bn < Q_SIZE);
                const float l2r = 13.287712379549449f / 64.0f;
                const float sc = 0.08838834764831845f;
                unsigned short* rowp;
                if (is_q) rowp = Qb + (size_t)(bm + r) * Q_SIZE + (bn >> 7) * HEAD_DIM;
                else      rowp = Kb + ((size_t)((bn - Q_SIZE) >> 7) * T_SEQ + bm + r) * HEAD_DIM;

                #pragma unroll
                for (int f4 = 0; f4 < 32; f4 += 4) {
                    ushort4 lo, hi;
                    #pragma unroll
                    for (int e = 0; e < 4; ++e) {
                        int f = ph * 32 + f4 + e;
                        float x1 = b2f(xnL[f * 132 + r]);          // d = f
                        float x2 = b2f(xnL[(f + 64) * 132 + r]);   // d = f+64
                        float s, c;
                        __sincosf(pos * exp2f(-(float)f * l2r), &s, &c);
                        float olo = fmaf(x1, c, -x2 * s);
                        float ohi = fmaf(x2, c,  x1 * s);
                        if (is_q) { olo *= sc; ohi *= sc; }
                        ((unsigned short*)&lo)[e] = f2bf(olo);
                        ((unsigned short*)&hi)[e] = f2bf(ohi);
                    }
                    *(ushort4*)(rowp + ph * 32 + f4)      = lo;
                    *(ushort4*)(rowp + 64 + ph * 32 + f4) = hi;
                }
            }
        } else {
            const int kvh = (bn - QK_N) >> 7;
            #pragma unroll
            for (int i = 0; i < 4; ++i)
                #pragma unroll
                for (int j = 0; j < 4; ++j) {
                    int d = wn + j * 16 + colL;
                    int tok = bm + wm + i * 16 + quad * 4;
                    ushort4 o;
                    o.x = f2bf(acc[i][j][0]); o.y = f2bf(acc[i][j][1]);
                    o.z = f2bf(acc[i][j][2]); o.w = f2bf(acc[i][j][3]);
                    *(ushort4*)&Vt[((size_t)kvh * HEAD_DIM + d) * T_SEQ + tok] = o;
                }
        }
    }
}

// ---------------------------------------------------------------------------
// Flash attention: BK=64, split-K over 1024-token chunks, fixed-max softmax,
// ones-column l, heavy-first ordering — unchanged.
// ---------------------------------------------------------------------------
#define BQ 64
#define BK 64

__global__ __launch_bounds__(256) void attn_mfma(
    const unsigned short* __restrict__ Qb, const unsigned short* __restrict__ Kb,
    const unsigned short* __restrict__ Vt, unsigned short* __restrict__ ctxb,
    float* __restrict__ partO, float* __restrict__ partL)
{
    const int h = blockIdx.y;
    int qt, ch;
    {
        int x = blockIdx.x;
        if (x < 16) { qt = 16 + x; ch = 0; }
        else {
            int p = (x - 16) >> 1;
            if (((x - 16) & 1) == 0) { qt = 15 - p; ch = 0; }
            else                     { qt = 31 - p; ch = 1; }
        }
    }
    const int nch = (qt >= 16) ? 2 : 1;
    const int units = (ch == 0) ? ((qt + 1 < 16) ? qt + 1 : 16) : (qt + 1 - 16);
    const int q0 = qt * BQ;
    const int kv = h >> 1;
    const int tid = threadIdx.x;
    const int w = tid >> 6;
    const int lane = tid & 63;
    const int col = lane & 15;
    const int quad = lane >> 4;

    __shared__ unsigned short Ks[2][64 * 128];
    __shared__ unsigned short Vs[2][144 * 64];
    __shared__ unsigned short Ps[4][16][72];

    {
        int x = tid * 4;
        unsigned short vv = (x < 64) ? (unsigned short)0x3F80 : (unsigned short)0;
        ushort4 o = {vv, vv, vv, vv};
        *(ushort4*)&Vs[0][128 * 64 + x] = o;
        *(ushort4*)&Vs[1][128 * 64 + x] = o;
    }

    short8 qf[4];
    {
        const unsigned short* qp = Qb + (size_t)(q0 + w * 16 + col) * Q_SIZE + h * HEAD_DIM;
        #pragma unroll
        for (int c = 0; c < 4; ++c)
            qf[c] = *(const short8*)(qp + c * 32 + quad * 8);
    }

    const unsigned short* kg[4];
    const unsigned short* vg[4];
    #pragma unroll
    for (int it = 0; it < 4; ++it) {
        int s = it * 256 + tid;
        int kr = s >> 4, kp = s & 15, kj = kp ^ (kr & 15);
        kg[it] = Kb + (size_t)kv * T_SEQ * HEAD_DIM + kr * HEAD_DIM + kj * 8;
        int vr = s >> 3, vp = s & 7, vj = vp ^ (vr & 7);
        vg[it] = Vt + (size_t)kv * HEAD_DIM * T_SEQ + (size_t)vr * T_SEQ + vj * 8;
    }

    floatx4 Ob[9];
    #pragma unroll
    for (int cb = 0; cb < 9; ++cb) Ob[cb] = (floatx4){0.f, 0.f, 0.f, 0.f};

    const int wave_qmin = q0 + w * 16;
    const int wave_qmax = wave_qmin + 15;
    const int tok_base = ch * 1024;

    #pragma unroll
    for (int it = 0; it < 4; ++it) {
        stage16(kg[it] + (size_t)tok_base * HEAD_DIM, &Ks[0][(it * 256 + w * 64) * 8]);
        stage16(vg[it] + tok_base, &Vs[0][(it * 256 + w * 64) * 8]);
    }

    for (int u = 0; u < units; ++u) {
        const int t0 = tok_base + u * BK;
        __syncthreads();
        if (u + 1 < units) {
            const int tn = t0 + BK;
            const int b = (u + 1) & 1;
            #pragma unroll
            for (int it = 0; it < 4; ++it) {
                stage16(kg[it] + (size_t)tn * HEAD_DIM, &Ks[b][(it * 256 + w * 64) * 8]);
                stage16(vg[it] + tn, &Vs[b][(it * 256 + w * 64) * 8]);
            }
        }
        if (t0 > wave_qmax) continue;
        const unsigned short* ks = Ks[u & 1];
        const unsigned short* vs = Vs[u & 1];

        floatx4 S[4];
        #pragma unroll
        for (int cb = 0; cb < 4; ++cb) {
            floatx4 a = (floatx4){0.f, 0.f, 0.f, 0.f};
            #pragma unroll
            for (int c = 0; c < 4; ++c) {
                short8 kf = *(const short8*)&ks[((cb * 16 + col) * 16 + ((c * 4 + quad) ^ col)) * 8];
                a = __builtin_amdgcn_mfma_f32_16x16x32_bf16(kf, qf[c], a, 0, 0, 0);
            }
            S[cb] = a;
        }

        const int qr = q0 + w * 16 + col;
        if (t0 + 63 <= wave_qmin) {
            #pragma unroll
            for (int cb = 0; cb < 4; ++cb) {
                ushort4 pk;
                pk.x = f2bf(__expf(S[cb][0])); pk.y = f2bf(__expf(S[cb][1]));
                pk.z = f2bf(__expf(S[cb][2])); pk.w = f2bf(__expf(S[cb][3]));
                *(ushort4*)&Ps[w][col][cb * 16 + quad * 4] = pk;
            }
        } else {
            #pragma unroll
            for (int cb = 0; cb < 4; ++cb) {
                int kt = t0 + cb * 16 + quad * 4;
                ushort4 pk;
                pk.x = (kt + 0 <= qr) ? f2bf(__expf(S[cb][0])) : (unsigned short)0;
                pk.y = (kt + 1 <= qr) ? f2bf(__expf(S[cb][1])) : (unsigned short)0;
                pk.z = (kt + 2 <= qr) ? f2bf(__expf(S[cb][2])) : (unsigned short)0;
                pk.w = (kt + 3 <= qr) ? f2bf(__expf(S[cb][3])) : (unsigned short)0;
                *(ushort4*)&Ps[w][col][cb * 16 + quad * 4] = pk;
            }
        }

        short8 pf[2];
        pf[0] = *(const short8*)&Ps[w][col][quad * 8];
        pf[1] = *(const short8*)&Ps[w][col][32 + quad * 8];
        #pragma unroll
        for (int cb = 0; cb < 9; ++cb) {
            int vrow = cb * 16 + col;
            #pragma unroll
            for (int kk = 0; kk < 2; ++kk) {
                short8 vf = *(const short8*)&vs[(vrow * 8 + ((kk * 4 + quad) ^ (vrow & 7))) * 8];
                Ob[cb] = __builtin_amdgcn_mfma_f32_16x16x32_bf16(pf[kk], vf, Ob[cb], 0, 0, 0);
            }
        }
    }

    if (nch == 1) {
        #pragma unroll
        for (int r = 0; r < 4; ++r) {
            float l = __shfl(Ob[8][r], lane & 48);
            float rl = 1.0f / l;
            const int qrow = q0 + w * 16 + quad * 4 + r;
            #pragma unroll
            for (int cb = 0; cb < 8; ++cb)
                ctxb[(size_t)qrow * Q_SIZE + h * HEAD_DIM + cb * 16 + col] = f2bf(Ob[cb][r] * rl);
        }
    } else {
        const int slot = (h * 16 + (qt - 16)) * 2 + ch;
        float* po = partO + (size_t)slot * (BQ * HEAD_DIM);
        #pragma unroll
        for (int cb = 0; cb < 8; ++cb)
            #pragma unroll
            for (int r = 0; r < 4; ++r)
                po[(w * 16 + quad * 4 + r) * HEAD_DIM + cb * 16 + col] = Ob[cb][r];
        if (col == 0) {
            #pragma unroll
            for (int r = 0; r < 4; ++r)
                partL[slot * BQ + w * 16 + quad * 4 + r] = Ob[8][r];
        }
    }
}

// ---------------------------------------------------------------------------
// Combine: ctx[qt>=16] = (O0 + O1) / (l0 + l1) — unchanged.
// ---------------------------------------------------------------------------
__global__ __launch_bounds__(256) void combine(
    const float* __restrict__ partO, const float* __restrict__ partL,
    unsigned short* __restrict__ ctxb)
{
    const int h = blockIdx.x >> 4;
    const int qi = blockIdx.x & 15;
    const int q0 = (16 + qi) * 64;
    const int slot0 = (h * 16 + qi) * 2;
    const int tid = threadIdx.x;
    const int row = tid >> 2;
    const int seg = tid & 3;

    const float l = partL[slot0 * 64 + row] + partL[(slot0 + 1) * 64 + row];
    const float rl = 1.0f / l;
    const float* p0 = partO + (size_t)slot0 * 8192 + row * 128 + seg * 32;
    const float* p1 = p0 + 8192;
    unsigned short* dst = ctxb + (size_t)(q0 + row) * Q_SIZE + h * HEAD_DIM + seg * 32;
    #pragma unroll
    for (int m = 0; m < 8; ++m) {
        float4 a = *(const float4*)(p0 + m * 4);
        float4 b = *(const float4*)(p1 + m * 4);
        ushort4 o;
        o.x = f2bf((a.x + b.x) * rl); o.y = f2bf((a.y + b.y) * rl);
        o.z = f2bf((a.z + b.z) * rl); o.w = f2bf((a.w + b.w) * rl);
        *(ushort4*)(dst + m * 4) = o;
    }
}

// ---------------------------------------------------------------------------
extern "C" void kernel_launch(void* const* d_in, const int* in_sizes, int n_in,
                              void* d_out, int out_size, void* d_ws, size_t ws_size,
                              hipStream_t stream)
{
    const int*   positions = (const int*)d_in[0];
    const float* hidden    = (const float*)d_in[1];
    const float* qkv_w     = (const float*)d_in[2];
    const float* q_norm_w  = (const float*)d_in[3];
    const float* k_norm_w  = (const float*)d_in[4];
    const float* o_w       = (const float*)d_in[5];
    float* out = (float*)d_out;

    const size_t MB = 1024 * 1024;
    char* ws = (char*)d_ws;
    unsigned short* obf  = (unsigned short*)ws;                 // [0,8)   whole run
    unsigned short* hbf  = (unsigned short*)(ws + 8 * MB);      // [8,16)  dead after QKV GEMM
    unsigned short* wbf  = (unsigned short*)(ws + 16 * MB);     // [16,32) dead after QKV GEMM
    unsigned short* Vt   = (unsigned short*)(ws + 32 * MB);     // [32,36)
    unsigned short* Qb   = (unsigned short*)(ws + 36 * MB);     // [36,44)
    unsigned short* Kb   = (unsigned short*)(ws + 44 * MB);     // [44,48)
    unsigned short* ctxb = (unsigned short*)(ws + 48 * MB);     // [48,56)
    float* partL         = (float*)(ws + 8 * MB);               // [8,8.125) over dead hbf
    float* partO         = (float*)(ws + 16 * MB);              // [16,32) over dead wbf (16 MB)

    convert_all<<<(H4 + W4 + O4 + 255) / 256, 256, 0, stream>>>(
        hidden, qkv_w, o_w, hbf, wbf, obf);
    gemm_nt_bf16<1><<<dim3(QKV_N / 128, T_SEQ / 128), 256, 0, stream>>>(
        hbf, wbf, nullptr, Qb, Kb, Vt, positions, q_norm_w, k_norm_w,
        T_SEQ, QKV_N, HIDDEN_);
    attn_mfma<<<dim3(48, NUM_HEADS), 256, 0, stream>>>(Qb, Kb, Vt, ctxb, partO, partL);
    combine<<<256, 256, 0, stream>>>(partO, partL, ctxb);
    gemm_nt_bf16<0><<<dim3(Q_SIZE / 128, T_SEQ / 128), 256, 0, stream>>>(
        ctxb, obf, out, nullptr, nullptr, nullptr, nullptr, nullptr, nullptr,
        T_SEQ, Q_SIZE, HIDDEN_);
}